// Round 6
// baseline (647.393 us; speedup 1.0000x reference)
//
#include <hip/hip_runtime.h>
#include <hip/hip_bf16.h>

#define D_IN  32
#define D_EF  16
#define D_H   64
#define D_MSG 32
#define D_UP  32

typedef float v2f __attribute__((ext_vector_type(2)));

// bf16 helpers: pack two fp32 -> uint32 (RNE), unpack low/high half
__device__ __forceinline__ unsigned bf16pair(float a, float b) {
    unsigned ua = __float_as_uint(a);
    ua = (ua + 0x7fffu + ((ua >> 16) & 1u)) >> 16;
    unsigned ub = __float_as_uint(b);
    ub = (ub + 0x7fffu + ((ub >> 16) & 1u)) >> 16;
    return ua | (ub << 16);
}
__device__ __forceinline__ float bf_lo(unsigned u) { return __uint_as_float(u << 16); }
__device__ __forceinline__ float bf_hi(unsigned u) { return __uint_as_float(u & 0xffff0000u); }

// ---------------------------------------------------------------------------
// Kernel 1: per-node precompute of the message-MLP first-layer partials.
//   P1[n] = x[n] @ W1m[0:32, :]  + b1m   (fp32, consumed by owning node n==dst)
//   P2[n] = x[n] @ W1m[32:64, :]         (bf16, gathered by src -> half traffic)
// ---------------------------------------------------------------------------
__global__ __launch_bounds__(256) void node_pre_kernel(
    const float* __restrict__ x,
    const float* __restrict__ W1m,
    const float* __restrict__ b1m,
    float* __restrict__ P1,
    unsigned short* __restrict__ P2b,
    int n_nodes)
{
    int i = blockIdx.x * blockDim.x + threadIdx.x;
    if (i >= n_nodes) return;

    float xi[D_IN];
    const float4* xp = (const float4*)(x + (size_t)i * D_IN);
#pragma unroll
    for (int k4 = 0; k4 < D_IN / 4; ++k4) {
        float4 v = xp[k4];
        xi[4 * k4 + 0] = v.x; xi[4 * k4 + 1] = v.y;
        xi[4 * k4 + 2] = v.z; xi[4 * k4 + 3] = v.w;
    }

    {
        float acc[D_H];
#pragma unroll
        for (int j = 0; j < D_H; ++j) acc[j] = b1m[j];
        for (int k = 0; k < D_IN; ++k) {
            float xv = xi[k];
            const float* wr = W1m + (size_t)k * D_H;
#pragma unroll
            for (int j = 0; j < D_H; ++j) acc[j] += xv * wr[j];
        }
        float4* o = (float4*)(P1 + (size_t)i * D_H);
#pragma unroll
        for (int j4 = 0; j4 < D_H / 4; ++j4)
            o[j4] = make_float4(acc[4 * j4], acc[4 * j4 + 1], acc[4 * j4 + 2], acc[4 * j4 + 3]);
    }
    {
        float acc[D_H];
#pragma unroll
        for (int j = 0; j < D_H; ++j) acc[j] = 0.0f;
        for (int k = 0; k < D_IN; ++k) {
            float xv = xi[k];
            const float* wr = W1m + (size_t)(k + D_IN) * D_H;
#pragma unroll
            for (int j = 0; j < D_H; ++j) acc[j] += xv * wr[j];
        }
        uint4* o = (uint4*)(P2b + (size_t)i * D_H);
#pragma unroll
        for (int j8 = 0; j8 < D_H / 8; ++j8) {
            uint4 q;
            q.x = bf16pair(acc[8 * j8 + 0], acc[8 * j8 + 1]);
            q.y = bf16pair(acc[8 * j8 + 2], acc[8 * j8 + 3]);
            q.z = bf16pair(acc[8 * j8 + 4], acc[8 * j8 + 5]);
            q.w = bf16pair(acc[8 * j8 + 6], acc[8 * j8 + 7]);
            o[j8] = q;
        }
    }
}

// ---------------------------------------------------------------------------
// CSR build: histogram -> 3-phase multi-block scan -> scatter
// ---------------------------------------------------------------------------
__global__ __launch_bounds__(256) void hist_kernel(
    const int* __restrict__ ei, int* __restrict__ deg, int n_edges)
{
    int e = blockIdx.x * blockDim.x + threadIdx.x;
    if (e < n_edges) atomicAdd(&deg[ei[n_edges + e]], 1);
}

// phase A: per-block sums of deg
__global__ __launch_bounds__(256) void scan_partials_kernel(
    const int* __restrict__ deg, int* __restrict__ bsum, int n_nodes)
{
    int idx = blockIdx.x * 256 + threadIdx.x;
    int v = (idx < n_nodes) ? deg[idx] : 0;
#pragma unroll
    for (int o = 1; o < 64; o <<= 1) v += __shfl_xor(v, o, 64);
    __shared__ int ws[4];
    int lane = threadIdx.x & 63, w = threadIdx.x >> 6;
    if (lane == 0) ws[w] = v;
    __syncthreads();
    if (threadIdx.x == 0) bsum[blockIdx.x] = ws[0] + ws[1] + ws[2] + ws[3];
}

// phase B: exclusive scan of the (<=256) block partials, one block
__global__ __launch_bounds__(256) void scan_blockoffs_kernel(
    const int* __restrict__ bsum, int* __restrict__ boffs, int nb)
{
    __shared__ int sdata[256];
    int t = threadIdx.x;
    sdata[t] = (t < nb) ? bsum[t] : 0;
    __syncthreads();
    for (int off = 1; off < 256; off <<= 1) {
        int u = (t >= off) ? sdata[t - off] : 0;
        __syncthreads();
        sdata[t] += u;
        __syncthreads();
    }
    if (t < nb) boffs[t] = (t > 0) ? sdata[t - 1] : 0;
}

// phase C: per-block local exclusive scan + block offset -> offs/cursor
__global__ __launch_bounds__(256) void scan_final_kernel(
    const int* __restrict__ deg, const int* __restrict__ boffs,
    int* __restrict__ offs, int* __restrict__ cursor, int n_nodes)
{
    __shared__ int sdata[256];
    int t = threadIdx.x;
    int idx = blockIdx.x * 256 + t;
    sdata[t] = (idx < n_nodes) ? deg[idx] : 0;
    __syncthreads();
    for (int off = 1; off < 256; off <<= 1) {
        int u = (t >= off) ? sdata[t - off] : 0;
        __syncthreads();
        sdata[t] += u;
        __syncthreads();
    }
    int excl = boffs[blockIdx.x] + ((t > 0) ? sdata[t - 1] : 0);
    if (idx < n_nodes) { offs[idx] = excl; cursor[idx] = excl; }
}

// scatter: writes packed (edge_id, src) per slot so gather never touches ei.
__global__ __launch_bounds__(256) void scatter_kernel(
    const int* __restrict__ ei,
    int* __restrict__ cursor,
    int2* __restrict__ edges_sorted,
    int n_edges)
{
    int e = blockIdx.x * blockDim.x + threadIdx.x;
    if (e < n_edges) {
        int s = ei[e];
        int d = ei[n_edges + e];
        int pos = atomicAdd(&cursor[d], 1);
        edges_sorted[pos] = make_int2(e, s);
    }
}

// ---------------------------------------------------------------------------
// Gather-aggregate, chunked-h, software-pipelined, PACKED fp32 math.
// 16 threads per node.
//   For each edge in node n's bucket:
//     for chunk j of 8 h-components:
//       h8 = P1[n][8j..] + bf16(P2[src][8j..]) + ef[e] @ W1E[:, 8j..8j+8)
//       msg += relu(h8) @ W2m[8j..8j+8, :]
//   Inner FMA streams written as float2 ext-vectors so clang emits
//   v_pk_fma_f32 (round-5 profile: VALU-issue ~157 us == scalar-FMA count;
//   fp32 peak requires packed ops). Predicted VALU-issue ~90 us.
// ---------------------------------------------------------------------------
__global__ __launch_bounds__(256) void gather_kernel(
    const float* __restrict__ ef,
    const float* __restrict__ W1m,
    const float* __restrict__ W2m,
    const float* __restrict__ P1,
    const unsigned short* __restrict__ P2b,
    const int*  __restrict__ deg,
    const int*  __restrict__ offs,
    const int2* __restrict__ edges_sorted,
    float* __restrict__ agg,
    int n_nodes)
{
    int tid = blockIdx.x * blockDim.x + threadIdx.x;
    int n = tid >> 4;
    int t = tid & 15;
    if (n >= n_nodes) return;

    int start = offs[n];
    int end   = start + deg[n];
    const float* W1E = W1m + (size_t)(2 * D_IN) * D_H;
    const float* P1n = P1 + (size_t)n * D_H;

    v2f msg2[D_MSG / 2];
#pragma unroll
    for (int m = 0; m < D_MSG / 2; ++m) msg2[m] = (v2f){0.0f, 0.0f};

    int i = start + t;
    int s = 0;
    float4 ef0, ef1, ef2, ef3;
    if (i < end) {
        int2 es = edges_sorted[i];
        s = es.y;
        const float4* efp = (const float4*)(ef + (size_t)es.x * D_EF);
        ef0 = efp[0]; ef1 = efp[1]; ef2 = efp[2]; ef3 = efp[3];
    }

    while (i < end) {
        // ---- prefetch next edge (clamped -> unconditional, always valid) ----
        int inext = i + 16;
        int ip = (inext < end) ? inext : i;
        int2 es2 = edges_sorted[ip];
        const float4* efp2 = (const float4*)(ef + (size_t)es2.x * D_EF);
        float4 nf0 = efp2[0], nf1 = efp2[1], nf2 = efp2[2], nf3 = efp2[3];

        float efr[D_EF] = {ef0.x, ef0.y, ef0.z, ef0.w,
                           ef1.x, ef1.y, ef1.z, ef1.w,
                           ef2.x, ef2.y, ef2.z, ef2.w,
                           ef3.x, ef3.y, ef3.z, ef3.w};

        const float4* p1  = (const float4*)P1n;
        const uint4*  p2u = (const uint4*)(P2b + (size_t)s * D_H);
        uint4 b = p2u[0];

#pragma unroll 1   // rolled: bounds code size; weight accesses stay uniform (s_load)
        for (int j = 0; j < D_H / 8; ++j) {
            int jn = (j < D_H / 8 - 1) ? (j + 1) : 0;
            uint4 c = p2u[jn];           // prefetch next chunk's P2 (bf16 x8)

            float4 a0 = p1[2 * j], a1 = p1[2 * j + 1];
            v2f h2[4];
            h2[0] = (v2f){a0.x + bf_lo(b.x), a0.y + bf_hi(b.x)};
            h2[1] = (v2f){a0.z + bf_lo(b.y), a0.w + bf_hi(b.y)};
            h2[2] = (v2f){a1.x + bf_lo(b.z), a1.y + bf_hi(b.z)};
            h2[3] = (v2f){a1.z + bf_lo(b.w), a1.w + bf_hi(b.w)};

#pragma unroll
            for (int k = 0; k < D_EF; ++k) {
                v2f ev2 = (v2f){efr[k], efr[k]};
                const v2f* wr2 = (const v2f*)(W1E + (size_t)k * D_H + 8 * j);
#pragma unroll
                for (int c4 = 0; c4 < 4; ++c4) h2[c4] += ev2 * wr2[c4];
            }

#pragma unroll
            for (int c8 = 0; c8 < 8; ++c8) {
                float hc = (c8 & 1) ? h2[c8 >> 1].y : h2[c8 >> 1].x;
                float r  = hc > 0.0f ? hc : 0.0f;
                v2f rv = (v2f){r, r};
                const v2f* wr2 = (const v2f*)(W2m + (size_t)(8 * j + c8) * D_MSG);
#pragma unroll
                for (int m = 0; m < D_MSG / 2; ++m) msg2[m] += rv * wr2[m];
            }
            b = c;
        }

        i = inext; s = es2.y;
        ef0 = nf0; ef1 = nf1; ef2 = nf2; ef3 = nf3;
    }

    // reduce partial msg across the node's 16 lanes
#pragma unroll
    for (int m = 0; m < D_MSG / 2; ++m) {
        float vx = msg2[m].x, vy = msg2[m].y;
        vx += __shfl_xor(vx, 1, 16);  vy += __shfl_xor(vy, 1, 16);
        vx += __shfl_xor(vx, 2, 16);  vy += __shfl_xor(vy, 2, 16);
        vx += __shfl_xor(vx, 4, 16);  vy += __shfl_xor(vy, 4, 16);
        vx += __shfl_xor(vx, 8, 16);  vy += __shfl_xor(vy, 8, 16);
        msg2[m].x = vx; msg2[m].y = vy;
    }

    if (t == 0) {
        float4* ap = (float4*)(agg + (size_t)n * D_MSG);
#pragma unroll
        for (int m4 = 0; m4 < D_MSG / 4; ++m4)
            ap[m4] = make_float4(msg2[2 * m4].x, msg2[2 * m4].y,
                                 msg2[2 * m4 + 1].x, msg2[2 * m4 + 1].y);
    }
}

// ---------------------------------------------------------------------------
// Per-node update MLP (adds deg[n]*b2m to agg on the fly).
//   out = relu([x, agg + deg*b2m] @ W1u + b1u) @ W2u + b2u
// ---------------------------------------------------------------------------
__global__ __launch_bounds__(256) void node_upd_kernel(
    const float* __restrict__ x,
    const float* __restrict__ agg,
    const int*   __restrict__ deg,
    const float* __restrict__ b2m,
    const float* __restrict__ W1u,
    const float* __restrict__ b1u,
    const float* __restrict__ W2u,
    const float* __restrict__ b2u,
    float* __restrict__ out,
    int n_nodes)
{
    int i = blockIdx.x * blockDim.x + threadIdx.x;
    if (i >= n_nodes) return;

    float in[D_IN + D_MSG];
    const float4* xp = (const float4*)(x + (size_t)i * D_IN);
#pragma unroll
    for (int k4 = 0; k4 < D_IN / 4; ++k4) {
        float4 v = xp[k4];
        in[4 * k4 + 0] = v.x; in[4 * k4 + 1] = v.y;
        in[4 * k4 + 2] = v.z; in[4 * k4 + 3] = v.w;
    }
    float dc = (float)deg[i];
    const float4* ap = (const float4*)(agg + (size_t)i * D_MSG);
#pragma unroll
    for (int k4 = 0; k4 < D_MSG / 4; ++k4) {
        float4 v = ap[k4];
        in[D_IN + 4 * k4 + 0] = v.x + dc * b2m[4 * k4 + 0];
        in[D_IN + 4 * k4 + 1] = v.y + dc * b2m[4 * k4 + 1];
        in[D_IN + 4 * k4 + 2] = v.z + dc * b2m[4 * k4 + 2];
        in[D_IN + 4 * k4 + 3] = v.w + dc * b2m[4 * k4 + 3];
    }

    float h[D_H];
#pragma unroll
    for (int j = 0; j < D_H; ++j) h[j] = b1u[j];
    for (int k = 0; k < D_IN + D_MSG; ++k) {
        float v = in[k];
        const float* wr = W1u + (size_t)k * D_H;
#pragma unroll
        for (int j = 0; j < D_H; ++j) h[j] += v * wr[j];
    }

    float o[D_UP];
#pragma unroll
    for (int m = 0; m < D_UP; ++m) o[m] = b2u[m];
    for (int j = 0; j < D_H; ++j) {
        float r = h[j] > 0.0f ? h[j] : 0.0f;
        const float* wr = W2u + (size_t)j * D_UP;
#pragma unroll
        for (int m = 0; m < D_UP; ++m) o[m] += r * wr[m];
    }

    float4* op = (float4*)(out + (size_t)i * D_UP);
#pragma unroll
    for (int m4 = 0; m4 < D_UP / 4; ++m4)
        op[m4] = make_float4(o[4 * m4], o[4 * m4 + 1], o[4 * m4 + 2], o[4 * m4 + 3]);
}

extern "C" void kernel_launch(void* const* d_in, const int* in_sizes, int n_in,
                              void* d_out, int out_size, void* d_ws, size_t ws_size,
                              hipStream_t stream) {
    const float* x    = (const float*)d_in[0];
    // d_in[1] = degrees — unused by the reference computation
    const float* ef   = (const float*)d_in[2];
    const float* W1m  = (const float*)d_in[3];
    const float* b1m  = (const float*)d_in[4];
    const float* W2m  = (const float*)d_in[5];
    const float* b2m  = (const float*)d_in[6];
    const float* W1u  = (const float*)d_in[7];
    const float* b1u  = (const float*)d_in[8];
    const float* W2u  = (const float*)d_in[9];
    const float* b2u  = (const float*)d_in[10];
    const int*   ei   = (const int*)d_in[11];

    const int n_nodes = in_sizes[0] / D_IN;      // 50000
    const int n_edges = in_sizes[11] / 2;        // 1600000

    float* out = (float*)d_out;

    const int NB = (n_nodes + 255) / 256;        // 196 scan blocks (<=256 req'd)

    // Workspace layout:
    //   agg          : n_nodes * D_MSG  f    (6.4 MB)
    //   P1           : n_nodes * D_H    f    (12.8 MB)
    //   P2b          : n_nodes * D_H    u16  (6.4 MB)
    //   edges_sorted : n_edges          int2 (12.8 MB)
    //   deg/offs/cursor : n_nodes       i
    //   bsum/boffs   : NB               i
    float*          agg = (float*)d_ws;
    float*          P1  = agg + (size_t)n_nodes * D_MSG;
    unsigned short* P2b = (unsigned short*)(P1 + (size_t)n_nodes * D_H);
    int2* edges_sorted  = (int2*)(P2b + (size_t)n_nodes * D_H);
    int* deg    = (int*)(edges_sorted + n_edges);
    int* offs   = deg    + n_nodes;
    int* cursor = offs   + n_nodes;
    int* bsum   = cursor + n_nodes;
    int* boffs  = bsum   + NB;

    hipMemsetAsync(deg, 0, (size_t)n_nodes * sizeof(int), stream);

    {
        int blk = 256;
        int grid = (n_nodes + blk - 1) / blk;
        node_pre_kernel<<<grid, blk, 0, stream>>>(x, W1m, b1m, P1, P2b, n_nodes);
    }
    {
        int blk = 256;
        int grid = (n_edges + blk - 1) / blk;
        hist_kernel<<<grid, blk, 0, stream>>>(ei, deg, n_edges);
    }
    scan_partials_kernel<<<NB, 256, 0, stream>>>(deg, bsum, n_nodes);
    scan_blockoffs_kernel<<<1, 256, 0, stream>>>(bsum, boffs, NB);
    scan_final_kernel<<<NB, 256, 0, stream>>>(deg, boffs, offs, cursor, n_nodes);
    {
        int blk = 256;
        int grid = (n_edges + blk - 1) / blk;
        scatter_kernel<<<grid, blk, 0, stream>>>(ei, cursor, edges_sorted, n_edges);
    }
    {
        int blk = 256;
        long total = (long)n_nodes * 16;
        int grid = (int)((total + blk - 1) / blk);
        gather_kernel<<<grid, blk, 0, stream>>>(ef, W1m, W2m, P1, P2b,
                                                deg, offs, edges_sorted, agg,
                                                n_nodes);
    }
    {
        int blk = 256;
        int grid = (n_nodes + blk - 1) / blk;
        node_upd_kernel<<<grid, blk, 0, stream>>>(x, agg, deg, b2m,
                                                  W1u, b1u, W2u, b2u, out, n_nodes);
    }
}

// Round 8
// 611.408 us; speedup vs baseline: 1.0589x; 1.0589x over previous
//
#include <hip/hip_runtime.h>
#include <hip/hip_bf16.h>

#define D_IN  32
#define D_EF  16
#define D_H   64
#define D_MSG 32
#define D_UP  32

// NOTE: __builtin_amdgcn_cvt_pkrtz / fdot2 use the __fp16-based vector type;
// _Float16-based ext vectors are treated as incompatible by clang (round-7
// compile failure).
typedef __fp16 v2h __attribute__((ext_vector_type(2)));

// bf16 helpers: pack two fp32 -> uint32 (RNE), unpack low/high half
__device__ __forceinline__ unsigned bf16pair(float a, float b) {
    unsigned ua = __float_as_uint(a);
    ua = (ua + 0x7fffu + ((ua >> 16) & 1u)) >> 16;
    unsigned ub = __float_as_uint(b);
    ub = (ub + 0x7fffu + ((ub >> 16) & 1u)) >> 16;
    return ua | (ub << 16);
}
__device__ __forceinline__ float bf_lo(unsigned u) { return __uint_as_float(u << 16); }
__device__ __forceinline__ float bf_hi(unsigned u) { return __uint_as_float(u & 0xffff0000u); }

// ---------------------------------------------------------------------------
// Kernel 1: per-node precompute of the message-MLP first-layer partials.
//   P1[n] = x[n] @ W1m[0:32, :]  + b1m   (fp32, consumed by owning node n==dst)
//   P2[n] = x[n] @ W1m[32:64, :]         (bf16, gathered by src -> half traffic)
// ---------------------------------------------------------------------------
__global__ __launch_bounds__(256) void node_pre_kernel(
    const float* __restrict__ x,
    const float* __restrict__ W1m,
    const float* __restrict__ b1m,
    float* __restrict__ P1,
    unsigned short* __restrict__ P2b,
    int n_nodes)
{
    int i = blockIdx.x * blockDim.x + threadIdx.x;
    if (i >= n_nodes) return;

    float xi[D_IN];
    const float4* xp = (const float4*)(x + (size_t)i * D_IN);
#pragma unroll
    for (int k4 = 0; k4 < D_IN / 4; ++k4) {
        float4 v = xp[k4];
        xi[4 * k4 + 0] = v.x; xi[4 * k4 + 1] = v.y;
        xi[4 * k4 + 2] = v.z; xi[4 * k4 + 3] = v.w;
    }

    {
        float acc[D_H];
#pragma unroll
        for (int j = 0; j < D_H; ++j) acc[j] = b1m[j];
        for (int k = 0; k < D_IN; ++k) {
            float xv = xi[k];
            const float* wr = W1m + (size_t)k * D_H;
#pragma unroll
            for (int j = 0; j < D_H; ++j) acc[j] += xv * wr[j];
        }
        float4* o = (float4*)(P1 + (size_t)i * D_H);
#pragma unroll
        for (int j4 = 0; j4 < D_H / 4; ++j4)
            o[j4] = make_float4(acc[4 * j4], acc[4 * j4 + 1], acc[4 * j4 + 2], acc[4 * j4 + 3]);
    }
    {
        float acc[D_H];
#pragma unroll
        for (int j = 0; j < D_H; ++j) acc[j] = 0.0f;
        for (int k = 0; k < D_IN; ++k) {
            float xv = xi[k];
            const float* wr = W1m + (size_t)(k + D_IN) * D_H;
#pragma unroll
            for (int j = 0; j < D_H; ++j) acc[j] += xv * wr[j];
        }
        uint4* o = (uint4*)(P2b + (size_t)i * D_H);
#pragma unroll
        for (int j8 = 0; j8 < D_H / 8; ++j8) {
            uint4 q;
            q.x = bf16pair(acc[8 * j8 + 0], acc[8 * j8 + 1]);
            q.y = bf16pair(acc[8 * j8 + 2], acc[8 * j8 + 3]);
            q.z = bf16pair(acc[8 * j8 + 4], acc[8 * j8 + 5]);
            q.w = bf16pair(acc[8 * j8 + 6], acc[8 * j8 + 7]);
            o[j8] = q;
        }
    }
}

// ---------------------------------------------------------------------------
// Weight pair-packing for v_dot2_f32_f16 (one tiny block, runs once per call):
//   W1Ep[kp*64+c] = half2(W1E[2kp][c],  W1E[2kp+1][c])   kp in [0,8)
//   W2p [jp*32+m] = half2(W2m[2jp][m],  W2m[2jp+1][m])   jp in [0,32)
// ---------------------------------------------------------------------------
__global__ __launch_bounds__(256) void pack_weights_kernel(
    const float* __restrict__ W1m,
    const float* __restrict__ W2m,
    v2h* __restrict__ W1Ep,
    v2h* __restrict__ W2p)
{
    int t = threadIdx.x;
    const float* W1E = W1m + (size_t)(2 * D_IN) * D_H;
    for (int idx = t; idx < 8 * D_H; idx += 256) {
        int kp = idx >> 6, c = idx & 63;
        W1Ep[idx] = __builtin_amdgcn_cvt_pkrtz(W1E[(2 * kp) * D_H + c],
                                               W1E[(2 * kp + 1) * D_H + c]);
    }
    for (int idx = t; idx < 32 * D_MSG; idx += 256) {
        int jp = idx >> 5, m = idx & 31;
        W2p[idx] = __builtin_amdgcn_cvt_pkrtz(W2m[(2 * jp) * D_MSG + m],
                                              W2m[(2 * jp + 1) * D_MSG + m]);
    }
}

// ---------------------------------------------------------------------------
// CSR build: histogram -> 3-phase multi-block scan -> scatter
// ---------------------------------------------------------------------------
__global__ __launch_bounds__(256) void hist_kernel(
    const int* __restrict__ ei, int* __restrict__ deg, int n_edges)
{
    int e = blockIdx.x * blockDim.x + threadIdx.x;
    if (e < n_edges) atomicAdd(&deg[ei[n_edges + e]], 1);
}

// phase A: per-block sums of deg
__global__ __launch_bounds__(256) void scan_partials_kernel(
    const int* __restrict__ deg, int* __restrict__ bsum, int n_nodes)
{
    int idx = blockIdx.x * 256 + threadIdx.x;
    int v = (idx < n_nodes) ? deg[idx] : 0;
#pragma unroll
    for (int o = 1; o < 64; o <<= 1) v += __shfl_xor(v, o, 64);
    __shared__ int ws[4];
    int lane = threadIdx.x & 63, w = threadIdx.x >> 6;
    if (lane == 0) ws[w] = v;
    __syncthreads();
    if (threadIdx.x == 0) bsum[blockIdx.x] = ws[0] + ws[1] + ws[2] + ws[3];
}

// phase B: exclusive scan of the (<=256) block partials, one block
__global__ __launch_bounds__(256) void scan_blockoffs_kernel(
    const int* __restrict__ bsum, int* __restrict__ boffs, int nb)
{
    __shared__ int sdata[256];
    int t = threadIdx.x;
    sdata[t] = (t < nb) ? bsum[t] : 0;
    __syncthreads();
    for (int off = 1; off < 256; off <<= 1) {
        int u = (t >= off) ? sdata[t - off] : 0;
        __syncthreads();
        sdata[t] += u;
        __syncthreads();
    }
    if (t < nb) boffs[t] = (t > 0) ? sdata[t - 1] : 0;
}

// phase C: per-block local exclusive scan + block offset -> offs/cursor
__global__ __launch_bounds__(256) void scan_final_kernel(
    const int* __restrict__ deg, const int* __restrict__ boffs,
    int* __restrict__ offs, int* __restrict__ cursor, int n_nodes)
{
    __shared__ int sdata[256];
    int t = threadIdx.x;
    int idx = blockIdx.x * 256 + t;
    sdata[t] = (idx < n_nodes) ? deg[idx] : 0;
    __syncthreads();
    for (int off = 1; off < 256; off <<= 1) {
        int u = (t >= off) ? sdata[t - off] : 0;
        __syncthreads();
        sdata[t] += u;
        __syncthreads();
    }
    int excl = boffs[blockIdx.x] + ((t > 0) ? sdata[t - 1] : 0);
    if (idx < n_nodes) { offs[idx] = excl; cursor[idx] = excl; }
}

// scatter: writes packed (edge_id, src) per slot so gather never touches ei.
__global__ __launch_bounds__(256) void scatter_kernel(
    const int* __restrict__ ei,
    int* __restrict__ cursor,
    int2* __restrict__ edges_sorted,
    int n_edges)
{
    int e = blockIdx.x * blockDim.x + threadIdx.x;
    if (e < n_edges) {
        int s = ei[e];
        int d = ei[n_edges + e];
        int pos = atomicAdd(&cursor[d], 1);
        edges_sorted[pos] = make_int2(e, s);
    }
}

// ---------------------------------------------------------------------------
// Gather-aggregate, chunked-h, v_dot2_f32_f16 math. 16 threads per node.
//   For each edge in node n's bucket:
//     for chunk j of 8 h-components:
//       h8 = P1[n][8j..] + bf16(P2[src][8j..]) + fp16 dot2(ef, W1Ep)
//       msg += dot2(pack(relu(h8)), W2p)
//   Round-6 showed float2 ext-vectors do NOT produce packed fp32 FMAs;
//   v_dot2_f32_f16 gives 2 MACs/inst with fp32 accumulate (one SGPR
//   operand allowed -> weight side stays scalar-loaded).
// ---------------------------------------------------------------------------
__global__ __launch_bounds__(256) void gather_kernel(
    const float* __restrict__ ef,
    const v2h*  __restrict__ W1Ep,
    const v2h*  __restrict__ W2p,
    const float* __restrict__ P1,
    const unsigned short* __restrict__ P2b,
    const int*  __restrict__ deg,
    const int*  __restrict__ offs,
    const int2* __restrict__ edges_sorted,
    float* __restrict__ agg,
    int n_nodes)
{
    int tid = blockIdx.x * blockDim.x + threadIdx.x;
    int n = tid >> 4;
    int t = tid & 15;
    if (n >= n_nodes) return;

    int start = offs[n];
    int end   = start + deg[n];
    const float* P1n = P1 + (size_t)n * D_H;

    float msg[D_MSG];
#pragma unroll
    for (int m = 0; m < D_MSG; ++m) msg[m] = 0.0f;

    int i = start + t;
    int s = 0;
    float4 ef0, ef1, ef2, ef3;
    if (i < end) {
        int2 es = edges_sorted[i];
        s = es.y;
        const float4* efp = (const float4*)(ef + (size_t)es.x * D_EF);
        ef0 = efp[0]; ef1 = efp[1]; ef2 = efp[2]; ef3 = efp[3];
    }

    while (i < end) {
        // ---- prefetch next edge (clamped -> unconditional, always valid) ----
        int inext = i + 16;
        int ip = (inext < end) ? inext : i;
        int2 es2 = edges_sorted[ip];
        const float4* efp2 = (const float4*)(ef + (size_t)es2.x * D_EF);
        float4 nf0 = efp2[0], nf1 = efp2[1], nf2 = efp2[2], nf3 = efp2[3];

        // current edge's ef -> fp16 pairs (k-pairs for dot2)
        v2h efh[D_EF / 2];
        efh[0] = __builtin_amdgcn_cvt_pkrtz(ef0.x, ef0.y);
        efh[1] = __builtin_amdgcn_cvt_pkrtz(ef0.z, ef0.w);
        efh[2] = __builtin_amdgcn_cvt_pkrtz(ef1.x, ef1.y);
        efh[3] = __builtin_amdgcn_cvt_pkrtz(ef1.z, ef1.w);
        efh[4] = __builtin_amdgcn_cvt_pkrtz(ef2.x, ef2.y);
        efh[5] = __builtin_amdgcn_cvt_pkrtz(ef2.z, ef2.w);
        efh[6] = __builtin_amdgcn_cvt_pkrtz(ef3.x, ef3.y);
        efh[7] = __builtin_amdgcn_cvt_pkrtz(ef3.z, ef3.w);

        const float4* p1  = (const float4*)P1n;
        const uint4*  p2u = (const uint4*)(P2b + (size_t)s * D_H);
        uint4 b = p2u[0];

#pragma unroll 1   // rolled: bounds code size; weight accesses stay uniform (s_load)
        for (int j = 0; j < D_H / 8; ++j) {
            int jn = (j < D_H / 8 - 1) ? (j + 1) : 0;
            uint4 c = p2u[jn];           // prefetch next chunk's P2 (bf16 x8)

            float4 a0 = p1[2 * j], a1 = p1[2 * j + 1];
            float h[8];
            h[0] = a0.x + bf_lo(b.x); h[1] = a0.y + bf_hi(b.x);
            h[2] = a0.z + bf_lo(b.y); h[3] = a0.w + bf_hi(b.y);
            h[4] = a1.x + bf_lo(b.z); h[5] = a1.y + bf_hi(b.z);
            h[6] = a1.z + bf_lo(b.w); h[7] = a1.w + bf_hi(b.w);

            // layer-1: h[c] += ef · W1E[:, 8j+c]  (8 k-pairs per column)
#pragma unroll
            for (int kp = 0; kp < D_EF / 2; ++kp) {
                const v2h* wr = W1Ep + kp * D_H + 8 * j;
#pragma unroll
                for (int c8 = 0; c8 < 8; ++c8)
                    h[c8] = __builtin_amdgcn_fdot2(efh[kp], wr[c8], h[c8], false);
            }

            // relu + pack h pairs to fp16
            v2h hp[4];
#pragma unroll
            for (int cp = 0; cp < 4; ++cp) {
                float r0 = h[2 * cp]     > 0.0f ? h[2 * cp]     : 0.0f;
                float r1 = h[2 * cp + 1] > 0.0f ? h[2 * cp + 1] : 0.0f;
                hp[cp] = __builtin_amdgcn_cvt_pkrtz(r0, r1);
            }

            // layer-2: msg[m] += relu(h) · W2m[:, m]  (j-pairs)
#pragma unroll
            for (int cp = 0; cp < 4; ++cp) {
                const v2h* wr2 = W2p + (size_t)(4 * j + cp) * D_MSG;
#pragma unroll
                for (int m = 0; m < D_MSG; ++m)
                    msg[m] = __builtin_amdgcn_fdot2(hp[cp], wr2[m], msg[m], false);
            }
            b = c;
        }

        i = inext; s = es2.y;
        ef0 = nf0; ef1 = nf1; ef2 = nf2; ef3 = nf3;
    }

    // reduce partial msg across the node's 16 lanes
#pragma unroll
    for (int m = 0; m < D_MSG; ++m) {
        float v = msg[m];
        v += __shfl_xor(v, 1, 16);
        v += __shfl_xor(v, 2, 16);
        v += __shfl_xor(v, 4, 16);
        v += __shfl_xor(v, 8, 16);
        msg[m] = v;
    }

    if (t == 0) {
        float4* ap = (float4*)(agg + (size_t)n * D_MSG);
#pragma unroll
        for (int m4 = 0; m4 < D_MSG / 4; ++m4)
            ap[m4] = make_float4(msg[4 * m4], msg[4 * m4 + 1],
                                 msg[4 * m4 + 2], msg[4 * m4 + 3]);
    }
}

// ---------------------------------------------------------------------------
// Per-node update MLP (adds deg[n]*b2m to agg on the fly).
//   out = relu([x, agg + deg*b2m] @ W1u + b1u) @ W2u + b2u
// ---------------------------------------------------------------------------
__global__ __launch_bounds__(256) void node_upd_kernel(
    const float* __restrict__ x,
    const float* __restrict__ agg,
    const int*   __restrict__ deg,
    const float* __restrict__ b2m,
    const float* __restrict__ W1u,
    const float* __restrict__ b1u,
    const float* __restrict__ W2u,
    const float* __restrict__ b2u,
    float* __restrict__ out,
    int n_nodes)
{
    int i = blockIdx.x * blockDim.x + threadIdx.x;
    if (i >= n_nodes) return;

    float in[D_IN + D_MSG];
    const float4* xp = (const float4*)(x + (size_t)i * D_IN);
#pragma unroll
    for (int k4 = 0; k4 < D_IN / 4; ++k4) {
        float4 v = xp[k4];
        in[4 * k4 + 0] = v.x; in[4 * k4 + 1] = v.y;
        in[4 * k4 + 2] = v.z; in[4 * k4 + 3] = v.w;
    }
    float dc = (float)deg[i];
    const float4* ap = (const float4*)(agg + (size_t)i * D_MSG);
#pragma unroll
    for (int k4 = 0; k4 < D_MSG / 4; ++k4) {
        float4 v = ap[k4];
        in[D_IN + 4 * k4 + 0] = v.x + dc * b2m[4 * k4 + 0];
        in[D_IN + 4 * k4 + 1] = v.y + dc * b2m[4 * k4 + 1];
        in[D_IN + 4 * k4 + 2] = v.z + dc * b2m[4 * k4 + 2];
        in[D_IN + 4 * k4 + 3] = v.w + dc * b2m[4 * k4 + 3];
    }

    float h[D_H];
#pragma unroll
    for (int j = 0; j < D_H; ++j) h[j] = b1u[j];
    for (int k = 0; k < D_IN + D_MSG; ++k) {
        float v = in[k];
        const float* wr = W1u + (size_t)k * D_H;
#pragma unroll
        for (int j = 0; j < D_H; ++j) h[j] += v * wr[j];
    }

    float o[D_UP];
#pragma unroll
    for (int m = 0; m < D_UP; ++m) o[m] = b2u[m];
    for (int j = 0; j < D_H; ++j) {
        float r = h[j] > 0.0f ? h[j] : 0.0f;
        const float* wr = W2u + (size_t)j * D_UP;
#pragma unroll
        for (int m = 0; m < D_UP; ++m) o[m] += r * wr[m];
    }

    float4* op = (float4*)(out + (size_t)i * D_UP);
#pragma unroll
    for (int m4 = 0; m4 < D_UP / 4; ++m4)
        op[m4] = make_float4(o[4 * m4], o[4 * m4 + 1], o[4 * m4 + 2], o[4 * m4 + 3]);
}

extern "C" void kernel_launch(void* const* d_in, const int* in_sizes, int n_in,
                              void* d_out, int out_size, void* d_ws, size_t ws_size,
                              hipStream_t stream) {
    const float* x    = (const float*)d_in[0];
    // d_in[1] = degrees — unused by the reference computation
    const float* ef   = (const float*)d_in[2];
    const float* W1m  = (const float*)d_in[3];
    const float* b1m  = (const float*)d_in[4];
    const float* W2m  = (const float*)d_in[5];
    const float* b2m  = (const float*)d_in[6];
    const float* W1u  = (const float*)d_in[7];
    const float* b1u  = (const float*)d_in[8];
    const float* W2u  = (const float*)d_in[9];
    const float* b2u  = (const float*)d_in[10];
    const int*   ei   = (const int*)d_in[11];

    const int n_nodes = in_sizes[0] / D_IN;      // 50000
    const int n_edges = in_sizes[11] / 2;        // 1600000

    float* out = (float*)d_out;

    const int NB = (n_nodes + 255) / 256;        // 196 scan blocks (<=256 req'd)

    // Workspace layout:
    //   agg          : n_nodes * D_MSG  f    (6.4 MB)
    //   P1           : n_nodes * D_H    f    (12.8 MB)
    //   P2b          : n_nodes * D_H    u16  (6.4 MB)
    //   edges_sorted : n_edges          int2 (12.8 MB)
    //   deg/offs/cursor : n_nodes       i
    //   bsum/boffs   : NB               i
    //   W1Ep         : 8*64   v2h (2 KB)
    //   W2p          : 32*32  v2h (4 KB)
    float*          agg = (float*)d_ws;
    float*          P1  = agg + (size_t)n_nodes * D_MSG;
    unsigned short* P2b = (unsigned short*)(P1 + (size_t)n_nodes * D_H);
    int2* edges_sorted  = (int2*)(P2b + (size_t)n_nodes * D_H);
    int* deg    = (int*)(edges_sorted + n_edges);
    int* offs   = deg    + n_nodes;
    int* cursor = offs   + n_nodes;
    int* bsum   = cursor + n_nodes;
    int* boffs  = bsum   + NB;
    v2h* W1Ep   = (v2h*)(boffs + NB);
    v2h* W2p    = W1Ep + 8 * D_H;

    hipMemsetAsync(deg, 0, (size_t)n_nodes * sizeof(int), stream);

    pack_weights_kernel<<<1, 256, 0, stream>>>(W1m, W2m, W1Ep, W2p);
    {
        int blk = 256;
        int grid = (n_nodes + blk - 1) / blk;
        node_pre_kernel<<<grid, blk, 0, stream>>>(x, W1m, b1m, P1, P2b, n_nodes);
    }
    {
        int blk = 256;
        int grid = (n_edges + blk - 1) / blk;
        hist_kernel<<<grid, blk, 0, stream>>>(ei, deg, n_edges);
    }
    scan_partials_kernel<<<NB, 256, 0, stream>>>(deg, bsum, n_nodes);
    scan_blockoffs_kernel<<<1, 256, 0, stream>>>(bsum, boffs, NB);
    scan_final_kernel<<<NB, 256, 0, stream>>>(deg, boffs, offs, cursor, n_nodes);
    {
        int blk = 256;
        int grid = (n_edges + blk - 1) / blk;
        scatter_kernel<<<grid, blk, 0, stream>>>(ei, cursor, edges_sorted, n_edges);
    }
    {
        int blk = 256;
        long total = (long)n_nodes * 16;
        int grid = (int)((total + blk - 1) / blk);
        gather_kernel<<<grid, blk, 0, stream>>>(ef, W1Ep, W2p, P1, P2b,
                                                deg, offs, edges_sorted, agg,
                                                n_nodes);
    }
    {
        int blk = 256;
        int grid = (n_nodes + blk - 1) / blk;
        node_upd_kernel<<<grid, blk, 0, stream>>>(x, agg, deg, b2m,
                                                  W1u, b1u, W2u, b2u, out, n_nodes);
    }
}

// Round 9
// 495.665 us; speedup vs baseline: 1.3061x; 1.2335x over previous
//
#include <hip/hip_runtime.h>
#include <hip/hip_bf16.h>

#define D_IN  32
#define D_EF  16
#define D_H   64
#define D_MSG 32
#define D_UP  32

// NOTE: __builtin_amdgcn_cvt_pkrtz / fdot2 use the __fp16-based vector type;
// _Float16-based ext vectors are treated as incompatible by clang (round-7
// compile failure).
typedef __fp16 v2h __attribute__((ext_vector_type(2)));

// bf16 helpers: pack two fp32 -> uint32 (RNE), unpack low/high half
__device__ __forceinline__ unsigned bf16pair(float a, float b) {
    unsigned ua = __float_as_uint(a);
    ua = (ua + 0x7fffu + ((ua >> 16) & 1u)) >> 16;
    unsigned ub = __float_as_uint(b);
    ub = (ub + 0x7fffu + ((ub >> 16) & 1u)) >> 16;
    return ua | (ub << 16);
}
__device__ __forceinline__ float bf_lo(unsigned u) { return __uint_as_float(u << 16); }
__device__ __forceinline__ float bf_hi(unsigned u) { return __uint_as_float(u & 0xffff0000u); }

// ---------------------------------------------------------------------------
// Fused front-end (independent stages dispatched by block range):
//   blocks [0, NBn)            : node_pre  (P1 fp32, P2 bf16 precompute)
//   blocks [NBn, NBn+NBe)      : hist + rank capture:
//                                  rank[e] = atomicAdd(&deg[dst[e]], 1)
//                                (rank makes the later scatter atomic-free)
//   block  NBn+NBe             : weight pair-packing for fdot2
// ---------------------------------------------------------------------------
__global__ __launch_bounds__(256) void prep_kernel(
    const float* __restrict__ x,
    const float* __restrict__ W1m,
    const float* __restrict__ b1m,
    const float* __restrict__ W2m,
    const int*   __restrict__ ei,
    float* __restrict__ P1,
    unsigned short* __restrict__ P2b,
    int* __restrict__ deg,
    int* __restrict__ rank,
    v2h* __restrict__ W1Ep,
    v2h* __restrict__ W2p,
    int n_nodes, int n_edges, int NBn, int NBe)
{
    int b = blockIdx.x;

    if (b < NBn) {
        // ---------------- node_pre ----------------
        int i = b * 256 + threadIdx.x;
        if (i >= n_nodes) return;

        float xi[D_IN];
        const float4* xp = (const float4*)(x + (size_t)i * D_IN);
#pragma unroll
        for (int k4 = 0; k4 < D_IN / 4; ++k4) {
            float4 v = xp[k4];
            xi[4 * k4 + 0] = v.x; xi[4 * k4 + 1] = v.y;
            xi[4 * k4 + 2] = v.z; xi[4 * k4 + 3] = v.w;
        }
        {
            float acc[D_H];
#pragma unroll
            for (int j = 0; j < D_H; ++j) acc[j] = b1m[j];
            for (int k = 0; k < D_IN; ++k) {
                float xv = xi[k];
                const float* wr = W1m + (size_t)k * D_H;
#pragma unroll
                for (int j = 0; j < D_H; ++j) acc[j] += xv * wr[j];
            }
            float4* o = (float4*)(P1 + (size_t)i * D_H);
#pragma unroll
            for (int j4 = 0; j4 < D_H / 4; ++j4)
                o[j4] = make_float4(acc[4 * j4], acc[4 * j4 + 1],
                                    acc[4 * j4 + 2], acc[4 * j4 + 3]);
        }
        {
            float acc[D_H];
#pragma unroll
            for (int j = 0; j < D_H; ++j) acc[j] = 0.0f;
            for (int k = 0; k < D_IN; ++k) {
                float xv = xi[k];
                const float* wr = W1m + (size_t)(k + D_IN) * D_H;
#pragma unroll
                for (int j = 0; j < D_H; ++j) acc[j] += xv * wr[j];
            }
            uint4* o = (uint4*)(P2b + (size_t)i * D_H);
#pragma unroll
            for (int j8 = 0; j8 < D_H / 8; ++j8) {
                uint4 q;
                q.x = bf16pair(acc[8 * j8 + 0], acc[8 * j8 + 1]);
                q.y = bf16pair(acc[8 * j8 + 2], acc[8 * j8 + 3]);
                q.z = bf16pair(acc[8 * j8 + 4], acc[8 * j8 + 5]);
                q.w = bf16pair(acc[8 * j8 + 6], acc[8 * j8 + 7]);
                o[j8] = q;
            }
        }
    } else if (b < NBn + NBe) {
        // ---------------- hist + rank ----------------
        int e = (b - NBn) * 256 + threadIdx.x;
        if (e < n_edges)
            rank[e] = atomicAdd(&deg[ei[n_edges + e]], 1);
    } else {
        // ---------------- pack weights ----------------
        int t = threadIdx.x;
        const float* W1E = W1m + (size_t)(2 * D_IN) * D_H;
        for (int idx = t; idx < 8 * D_H; idx += 256) {
            int kp = idx >> 6, c = idx & 63;
            W1Ep[idx] = __builtin_amdgcn_cvt_pkrtz(W1E[(2 * kp) * D_H + c],
                                                   W1E[(2 * kp + 1) * D_H + c]);
        }
        for (int idx = t; idx < 32 * D_MSG; idx += 256) {
            int jp = idx >> 5, m = idx & 31;
            W2p[idx] = __builtin_amdgcn_cvt_pkrtz(W2m[(2 * jp) * D_MSG + m],
                                                  W2m[(2 * jp + 1) * D_MSG + m]);
        }
    }
}

// ---------------------------------------------------------------------------
// 3-phase multi-block exclusive scan of deg -> offs
// ---------------------------------------------------------------------------
__global__ __launch_bounds__(256) void scan_partials_kernel(
    const int* __restrict__ deg, int* __restrict__ bsum, int n_nodes)
{
    int idx = blockIdx.x * 256 + threadIdx.x;
    int v = (idx < n_nodes) ? deg[idx] : 0;
#pragma unroll
    for (int o = 1; o < 64; o <<= 1) v += __shfl_xor(v, o, 64);
    __shared__ int ws[4];
    int lane = threadIdx.x & 63, w = threadIdx.x >> 6;
    if (lane == 0) ws[w] = v;
    __syncthreads();
    if (threadIdx.x == 0) bsum[blockIdx.x] = ws[0] + ws[1] + ws[2] + ws[3];
}

__global__ __launch_bounds__(256) void scan_blockoffs_kernel(
    const int* __restrict__ bsum, int* __restrict__ boffs, int nb)
{
    __shared__ int sdata[256];
    int t = threadIdx.x;
    sdata[t] = (t < nb) ? bsum[t] : 0;
    __syncthreads();
    for (int off = 1; off < 256; off <<= 1) {
        int u = (t >= off) ? sdata[t - off] : 0;
        __syncthreads();
        sdata[t] += u;
        __syncthreads();
    }
    if (t < nb) boffs[t] = (t > 0) ? sdata[t - 1] : 0;
}

__global__ __launch_bounds__(256) void scan_final_kernel(
    const int* __restrict__ deg, const int* __restrict__ boffs,
    int* __restrict__ offs, int n_nodes)
{
    __shared__ int sdata[256];
    int t = threadIdx.x;
    int idx = blockIdx.x * 256 + t;
    sdata[t] = (idx < n_nodes) ? deg[idx] : 0;
    __syncthreads();
    for (int off = 1; off < 256; off <<= 1) {
        int u = (t >= off) ? sdata[t - off] : 0;
        __syncthreads();
        sdata[t] += u;
        __syncthreads();
    }
    int excl = boffs[blockIdx.x] + ((t > 0) ? sdata[t - 1] : 0);
    if (idx < n_nodes) offs[idx] = excl;
}

// ---------------------------------------------------------------------------
// Atomic-free scatter: pos = offs[dst] + rank[e]  (unique by construction).
// Writes packed (edge_id, src) so gather never touches ei.
// ---------------------------------------------------------------------------
__global__ __launch_bounds__(256) void scatter_kernel(
    const int* __restrict__ ei,
    const int* __restrict__ rank,
    const int* __restrict__ offs,
    int2* __restrict__ edges_sorted,
    int n_edges)
{
    int e = blockIdx.x * blockDim.x + threadIdx.x;
    if (e < n_edges) {
        int s = ei[e];
        int d = ei[n_edges + e];
        int pos = offs[d] + rank[e];
        edges_sorted[pos] = make_int2(e, s);
    }
}

// ---------------------------------------------------------------------------
// Gather-aggregate, chunked-h, v_dot2_f32_f16 math. 16 threads per node.
//   For each edge in node n's bucket:
//     for chunk j of 8 h-components:
//       h8 = P1[n][8j..] + bf16(P2[src][8j..]) + fp16 dot2(ef, W1Ep)
//       msg += dot2(pack(relu(h8)), W2p)
// ---------------------------------------------------------------------------
__global__ __launch_bounds__(256) void gather_kernel(
    const float* __restrict__ ef,
    const v2h*  __restrict__ W1Ep,
    const v2h*  __restrict__ W2p,
    const float* __restrict__ P1,
    const unsigned short* __restrict__ P2b,
    const int*  __restrict__ deg,
    const int*  __restrict__ offs,
    const int2* __restrict__ edges_sorted,
    float* __restrict__ agg,
    int n_nodes)
{
    int tid = blockIdx.x * blockDim.x + threadIdx.x;
    int n = tid >> 4;
    int t = tid & 15;
    if (n >= n_nodes) return;

    int start = offs[n];
    int end   = start + deg[n];
    const float* P1n = P1 + (size_t)n * D_H;

    float msg[D_MSG];
#pragma unroll
    for (int m = 0; m < D_MSG; ++m) msg[m] = 0.0f;

    int i = start + t;
    int s = 0;
    float4 ef0, ef1, ef2, ef3;
    if (i < end) {
        int2 es = edges_sorted[i];
        s = es.y;
        const float4* efp = (const float4*)(ef + (size_t)es.x * D_EF);
        ef0 = efp[0]; ef1 = efp[1]; ef2 = efp[2]; ef3 = efp[3];
    }

    while (i < end) {
        // ---- prefetch next edge (clamped -> unconditional, always valid) ----
        int inext = i + 16;
        int ip = (inext < end) ? inext : i;
        int2 es2 = edges_sorted[ip];
        const float4* efp2 = (const float4*)(ef + (size_t)es2.x * D_EF);
        float4 nf0 = efp2[0], nf1 = efp2[1], nf2 = efp2[2], nf3 = efp2[3];

        // current edge's ef -> fp16 pairs (k-pairs for dot2)
        v2h efh[D_EF / 2];
        efh[0] = __builtin_amdgcn_cvt_pkrtz(ef0.x, ef0.y);
        efh[1] = __builtin_amdgcn_cvt_pkrtz(ef0.z, ef0.w);
        efh[2] = __builtin_amdgcn_cvt_pkrtz(ef1.x, ef1.y);
        efh[3] = __builtin_amdgcn_cvt_pkrtz(ef1.z, ef1.w);
        efh[4] = __builtin_amdgcn_cvt_pkrtz(ef2.x, ef2.y);
        efh[5] = __builtin_amdgcn_cvt_pkrtz(ef2.z, ef2.w);
        efh[6] = __builtin_amdgcn_cvt_pkrtz(ef3.x, ef3.y);
        efh[7] = __builtin_amdgcn_cvt_pkrtz(ef3.z, ef3.w);

        const float4* p1  = (const float4*)P1n;
        const uint4*  p2u = (const uint4*)(P2b + (size_t)s * D_H);
        uint4 b = p2u[0];

#pragma unroll 1   // rolled: bounds code size; weight accesses stay uniform (s_load)
        for (int j = 0; j < D_H / 8; ++j) {
            int jn = (j < D_H / 8 - 1) ? (j + 1) : 0;
            uint4 c = p2u[jn];           // prefetch next chunk's P2 (bf16 x8)

            float4 a0 = p1[2 * j], a1 = p1[2 * j + 1];
            float h[8];
            h[0] = a0.x + bf_lo(b.x); h[1] = a0.y + bf_hi(b.x);
            h[2] = a0.z + bf_lo(b.y); h[3] = a0.w + bf_hi(b.y);
            h[4] = a1.x + bf_lo(b.z); h[5] = a1.y + bf_hi(b.z);
            h[6] = a1.z + bf_lo(b.w); h[7] = a1.w + bf_hi(b.w);

            // layer-1: h[c] += ef · W1E[:, 8j+c]  (8 k-pairs per column)
#pragma unroll
            for (int kp = 0; kp < D_EF / 2; ++kp) {
                const v2h* wr = W1Ep + kp * D_H + 8 * j;
#pragma unroll
                for (int c8 = 0; c8 < 8; ++c8)
                    h[c8] = __builtin_amdgcn_fdot2(efh[kp], wr[c8], h[c8], false);
            }

            // relu + pack h pairs to fp16
            v2h hp[4];
#pragma unroll
            for (int cp = 0; cp < 4; ++cp) {
                float r0 = h[2 * cp]     > 0.0f ? h[2 * cp]     : 0.0f;
                float r1 = h[2 * cp + 1] > 0.0f ? h[2 * cp + 1] : 0.0f;
                hp[cp] = __builtin_amdgcn_cvt_pkrtz(r0, r1);
            }

            // layer-2: msg[m] += relu(h) · W2m[:, m]  (j-pairs)
#pragma unroll
            for (int cp = 0; cp < 4; ++cp) {
                const v2h* wr2 = W2p + (size_t)(4 * j + cp) * D_MSG;
#pragma unroll
                for (int m = 0; m < D_MSG; ++m)
                    msg[m] = __builtin_amdgcn_fdot2(hp[cp], wr2[m], msg[m], false);
            }
            b = c;
        }

        i = inext; s = es2.y;
        ef0 = nf0; ef1 = nf1; ef2 = nf2; ef3 = nf3;
    }

    // reduce partial msg across the node's 16 lanes
#pragma unroll
    for (int m = 0; m < D_MSG; ++m) {
        float v = msg[m];
        v += __shfl_xor(v, 1, 16);
        v += __shfl_xor(v, 2, 16);
        v += __shfl_xor(v, 4, 16);
        v += __shfl_xor(v, 8, 16);
        msg[m] = v;
    }

    if (t == 0) {
        float4* ap = (float4*)(agg + (size_t)n * D_MSG);
#pragma unroll
        for (int m4 = 0; m4 < D_MSG / 4; ++m4)
            ap[m4] = make_float4(msg[4 * m4], msg[4 * m4 + 1],
                                 msg[4 * m4 + 2], msg[4 * m4 + 3]);
    }
}

// ---------------------------------------------------------------------------
// Per-node update MLP (adds deg[n]*b2m to agg on the fly).
//   out = relu([x, agg + deg*b2m] @ W1u + b1u) @ W2u + b2u
// ---------------------------------------------------------------------------
__global__ __launch_bounds__(256) void node_upd_kernel(
    const float* __restrict__ x,
    const float* __restrict__ agg,
    const int*   __restrict__ deg,
    const float* __restrict__ b2m,
    const float* __restrict__ W1u,
    const float* __restrict__ b1u,
    const float* __restrict__ W2u,
    const float* __restrict__ b2u,
    float* __restrict__ out,
    int n_nodes)
{
    int i = blockIdx.x * blockDim.x + threadIdx.x;
    if (i >= n_nodes) return;

    float in[D_IN + D_MSG];
    const float4* xp = (const float4*)(x + (size_t)i * D_IN);
#pragma unroll
    for (int k4 = 0; k4 < D_IN / 4; ++k4) {
        float4 v = xp[k4];
        in[4 * k4 + 0] = v.x; in[4 * k4 + 1] = v.y;
        in[4 * k4 + 2] = v.z; in[4 * k4 + 3] = v.w;
    }
    float dc = (float)deg[i];
    const float4* ap = (const float4*)(agg + (size_t)i * D_MSG);
#pragma unroll
    for (int k4 = 0; k4 < D_MSG / 4; ++k4) {
        float4 v = ap[k4];
        in[D_IN + 4 * k4 + 0] = v.x + dc * b2m[4 * k4 + 0];
        in[D_IN + 4 * k4 + 1] = v.y + dc * b2m[4 * k4 + 1];
        in[D_IN + 4 * k4 + 2] = v.z + dc * b2m[4 * k4 + 2];
        in[D_IN + 4 * k4 + 3] = v.w + dc * b2m[4 * k4 + 3];
    }

    float h[D_H];
#pragma unroll
    for (int j = 0; j < D_H; ++j) h[j] = b1u[j];
    for (int k = 0; k < D_IN + D_MSG; ++k) {
        float v = in[k];
        const float* wr = W1u + (size_t)k * D_H;
#pragma unroll
        for (int j = 0; j < D_H; ++j) h[j] += v * wr[j];
    }

    float o[D_UP];
#pragma unroll
    for (int m = 0; m < D_UP; ++m) o[m] = b2u[m];
    for (int j = 0; j < D_H; ++j) {
        float r = h[j] > 0.0f ? h[j] : 0.0f;
        const float* wr = W2u + (size_t)j * D_UP;
#pragma unroll
        for (int m = 0; m < D_UP; ++m) o[m] += r * wr[m];
    }

    float4* op = (float4*)(out + (size_t)i * D_UP);
#pragma unroll
    for (int m4 = 0; m4 < D_UP / 4; ++m4)
        op[m4] = make_float4(o[4 * m4], o[4 * m4 + 1], o[4 * m4 + 2], o[4 * m4 + 3]);
}

extern "C" void kernel_launch(void* const* d_in, const int* in_sizes, int n_in,
                              void* d_out, int out_size, void* d_ws, size_t ws_size,
                              hipStream_t stream) {
    const float* x    = (const float*)d_in[0];
    // d_in[1] = degrees — unused by the reference computation
    const float* ef   = (const float*)d_in[2];
    const float* W1m  = (const float*)d_in[3];
    const float* b1m  = (const float*)d_in[4];
    const float* W2m  = (const float*)d_in[5];
    const float* b2m  = (const float*)d_in[6];
    const float* W1u  = (const float*)d_in[7];
    const float* b1u  = (const float*)d_in[8];
    const float* W2u  = (const float*)d_in[9];
    const float* b2u  = (const float*)d_in[10];
    const int*   ei   = (const int*)d_in[11];

    const int n_nodes = in_sizes[0] / D_IN;      // 50000
    const int n_edges = in_sizes[11] / 2;        // 1600000

    float* out = (float*)d_out;

    const int NBn = (n_nodes + 255) / 256;       // 196 node blocks (<=256 req'd for scan)
    const int NBe = (n_edges + 255) / 256;       // 6250 edge blocks

    // Workspace layout:
    //   agg          : n_nodes * D_MSG  f    (6.4 MB)
    //   P1           : n_nodes * D_H    f    (12.8 MB)
    //   P2b          : n_nodes * D_H    u16  (6.4 MB)
    //   edges_sorted : n_edges          int2 (12.8 MB)
    //   rank         : n_edges          i    (6.4 MB)
    //   deg/offs     : n_nodes          i
    //   bsum/boffs   : NBn              i
    //   W1Ep         : 8*64   v2h (2 KB)
    //   W2p          : 32*32  v2h (4 KB)
    float*          agg = (float*)d_ws;
    float*          P1  = agg + (size_t)n_nodes * D_MSG;
    unsigned short* P2b = (unsigned short*)(P1 + (size_t)n_nodes * D_H);
    int2* edges_sorted  = (int2*)(P2b + (size_t)n_nodes * D_H);
    int* rank   = (int*)(edges_sorted + n_edges);
    int* deg    = rank   + n_edges;
    int* offs   = deg    + n_nodes;
    int* bsum   = offs   + n_nodes;
    int* boffs  = bsum   + NBn;
    v2h* W1Ep   = (v2h*)(boffs + NBn);
    v2h* W2p    = W1Ep + 8 * D_H;

    hipMemsetAsync(deg, 0, (size_t)n_nodes * sizeof(int), stream);

    prep_kernel<<<NBn + NBe + 1, 256, 0, stream>>>(
        x, W1m, b1m, W2m, ei, P1, P2b, deg, rank, W1Ep, W2p,
        n_nodes, n_edges, NBn, NBe);

    scan_partials_kernel<<<NBn, 256, 0, stream>>>(deg, bsum, n_nodes);
    scan_blockoffs_kernel<<<1, 256, 0, stream>>>(bsum, boffs, NBn);
    scan_final_kernel<<<NBn, 256, 0, stream>>>(deg, boffs, offs, n_nodes);

    scatter_kernel<<<NBe, 256, 0, stream>>>(ei, rank, offs, edges_sorted, n_edges);

    {
        long total = (long)n_nodes * 16;
        int grid = (int)((total + 255) / 256);
        gather_kernel<<<grid, 256, 0, stream>>>(ef, W1Ep, W2p, P1, P2b,
                                                deg, offs, edges_sorted, agg,
                                                n_nodes);
    }
    node_upd_kernel<<<NBn, 256, 0, stream>>>(x, agg, deg, b2m,
                                             W1u, b1u, W2u, b2u, out, n_nodes);
}